// Round 2
// baseline (295.626 us; speedup 1.0000x reference)
//
#include <hip/hip_runtime.h>
#include <hip/hip_bf16.h>

typedef __attribute__((ext_vector_type(4))) float f32x4;
typedef __attribute__((ext_vector_type(8))) short bfx8;   // 8 bf16 = 4 VGPRs (MFMA A/B frag)

#define K_DIM 1024
#define N_DIM 1024

__device__ __forceinline__ ushort f2bf(float f) {
    uint u = __float_as_uint(f);
    u += 0x7fffu + ((u >> 16) & 1u);     // round-to-nearest-even
    return (ushort)(u >> 16);
}

// ---------------- f32 -> bf16 conversion of all 7 inputs ----------------
__global__ __launch_bounds__(256) void cvt_all(
    const float* __restrict__ q, const float* __restrict__ k, const float* __restrict__ v,
    const float* __restrict__ wq, const float* __restrict__ wk,
    const float* __restrict__ wv, const float* __restrict__ wo,
    ushort* __restrict__ ws)
{
    const int IN4 = 1 << 20;   // 4096*1024/4 float4 units per input
    const int W4  = 1 << 18;   // 1024*1024/4 per weight
    const int total = 3*IN4 + 4*W4;
    ushort4* dst4 = reinterpret_cast<ushort4*>(ws);
    for (int u = blockIdx.x*blockDim.x + threadIdx.x; u < total; u += gridDim.x*blockDim.x) {
        const float* src; int local, off;
        if (u < 3*IN4) {
            int op = u >> 20;
            local = u & (IN4-1);
            src = op==0 ? q : (op==1 ? k : v);
            off = op * IN4;
        } else {
            int t = u - 3*IN4;
            int op = t >> 18;
            local = t & (W4-1);
            src = op==0 ? wq : (op==1 ? wk : (op==2 ? wv : wo));
            off = 3*IN4 + op*W4;
        }
        float4 f = reinterpret_cast<const float4*>(src)[local];
        ushort4 o;
        o.x = f2bf(f.x); o.y = f2bf(f.y); o.z = f2bf(f.z); o.w = f2bf(f.w);
        dst4[off + local] = o;
    }
}

// ---------------- GEMM body: C[m][n] = sum_k A[m][k] * W[n][k], bf16 in ----
// 128x128 tile, BK=64, 4 waves (2x2 of 64x64), 16x16x32 bf16 MFMA.
// MODE 0: out bf16 [B][H][S][D]   (Q/K projection)
// MODE 1: out bf16 [B][H][D][S]   (V projection, transposed for PV reads)
// MODE 2: out f32  [M][N]         (final output -> d_out, reference dtype f32)
template<int MODE>
__device__ __forceinline__ void gemm_body(
    const ushort* __restrict__ A, const ushort* __restrict__ Bw,
    ushort* __restrict__ C, float* __restrict__ Cf,
    int blk, ushort* As, ushort* Bs)
{
    const int tid  = threadIdx.x;
    const int lane = tid & 63;
    const int wave = tid >> 6;
    const int tn = blk & 7;     // N/128 = 8
    const int tm = blk >> 3;    // M/128 = 32
    const int wr = wave >> 1, wc = wave & 1;

    f32x4 acc[4][4];
    #pragma unroll
    for (int a = 0; a < 4; ++a)
        #pragma unroll
        for (int b2 = 0; b2 < 4; ++b2)
            acc[a][b2] = (f32x4){0.f, 0.f, 0.f, 0.f};

    for (int k0 = 0; k0 < K_DIM; k0 += 64) {
        __syncthreads();   // prior compute done reading LDS
        // stage A,B tiles (128x64 bf16 each) with 16B-unit XOR swizzle
        #pragma unroll
        for (int j = 0; j < 4; ++j) {
            int u = tid + j*256;          // 1024 16B-units per matrix
            int row = u >> 3, col = u & 7;
            int slot = col ^ (row & 7);
            uint4 av = *reinterpret_cast<const uint4*>(A + (size_t)(tm*128 + row)*K_DIM + k0 + col*8);
            *reinterpret_cast<uint4*>(&As[row*64 + slot*8]) = av;
            uint4 bv = *reinterpret_cast<const uint4*>(Bw + (size_t)(tn*128 + row)*K_DIM + k0 + col*8);
            *reinterpret_cast<uint4*>(&Bs[row*64 + slot*8]) = bv;
        }
        __syncthreads();
        #pragma unroll
        for (int kk = 0; kk < 2; ++kk) {
            bfx8 af[4], bfr[4];
            #pragma unroll
            for (int mi = 0; mi < 4; ++mi) {
                int row  = wr*64 + mi*16 + (lane & 15);
                int unit = kk*4 + (lane >> 4);
                af[mi] = *reinterpret_cast<const bfx8*>(&As[row*64 + (unit ^ (row & 7))*8]);
            }
            #pragma unroll
            for (int ni = 0; ni < 4; ++ni) {
                int row  = wc*64 + ni*16 + (lane & 15);
                int unit = kk*4 + (lane >> 4);
                bfr[ni] = *reinterpret_cast<const bfx8*>(&Bs[row*64 + (unit ^ (row & 7))*8]);
            }
            #pragma unroll
            for (int mi = 0; mi < 4; ++mi)
                #pragma unroll
                for (int ni = 0; ni < 4; ++ni)
                    acc[mi][ni] = __builtin_amdgcn_mfma_f32_16x16x32_bf16(af[mi], bfr[ni], acc[mi][ni], 0, 0, 0);
        }
    }
    // epilogue: D layout col = lane&15, row = (lane>>4)*4 + i
    #pragma unroll
    for (int mi = 0; mi < 4; ++mi)
      #pragma unroll
      for (int ni = 0; ni < 4; ++ni)
        #pragma unroll
        for (int i = 0; i < 4; ++i) {
            int gr = tm*128 + wr*64 + mi*16 + (lane >> 4)*4 + i;   // m: b*2048+s
            int gc = tn*128 + wc*64 + ni*16 + (lane & 15);         // n: h*64+d
            if constexpr (MODE == 0) {
                int b = gr >> 11, s = gr & 2047, h = gc >> 6, d = gc & 63;
                C[(((size_t)(b*16 + h))*2048 + s)*64 + d] = f2bf(acc[mi][ni][i]);
            } else if constexpr (MODE == 1) {
                int b = gr >> 11, s = gr & 2047, h = gc >> 6, d = gc & 63;
                C[(((size_t)(b*16 + h))*64 + d)*2048 + s] = f2bf(acc[mi][ni][i]);
            } else {
                Cf[(size_t)gr*N_DIM + gc] = acc[mi][ni][i];
            }
        }
}

__global__ __launch_bounds__(256) void proj_kernel(
    const ushort* __restrict__ qb, const ushort* __restrict__ kb, const ushort* __restrict__ vb,
    const ushort* __restrict__ wqb, const ushort* __restrict__ wkb, const ushort* __restrict__ wvb,
    ushort* __restrict__ Qp, ushort* __restrict__ Kp, ushort* __restrict__ Vt)
{
    __shared__ ushort As[128*64];
    __shared__ ushort Bs[128*64];
    int op = blockIdx.y;
    if (op == 0)      gemm_body<0>(qb, wqb, Qp, nullptr, blockIdx.x, As, Bs);
    else if (op == 1) gemm_body<0>(kb, wkb, Kp, nullptr, blockIdx.x, As, Bs);
    else              gemm_body<1>(vb, wvb, Vt, nullptr, blockIdx.x, As, Bs);
}

__global__ __launch_bounds__(256) void outproj_kernel(
    const ushort* __restrict__ AO, const ushort* __restrict__ wob, float* __restrict__ out)
{
    __shared__ ushort As[128*64];
    __shared__ ushort Bs[128*64];
    gemm_body<2>(AO, wob, nullptr, out, blockIdx.x, As, Bs);
}

// ---------------- block-sparse attention ----------------
// grid: b(2) * h(16) * r(32) = 1024 blocks, 256 threads (4 waves, 16-row strips).
// For each c in [r-15, r+15]: S = Q K^T, per-pair softmax (scale 0.125), O += (P/rowsum) V.
__global__ __launch_bounds__(256) void attn_kernel(
    const ushort* __restrict__ Qp, const ushort* __restrict__ Kp,
    const ushort* __restrict__ Vt, ushort* __restrict__ AO)
{
    const int blk = blockIdx.x;
    const int r = blk & 31;
    const int h = (blk >> 5) & 15;
    const int b = blk >> 9;
    const int tid  = threadIdx.x;
    const int lane = tid & 63;
    const int wave = tid >> 6;

    __shared__ ushort Qs[64*64];
    __shared__ ushort Ks[64*64];
    __shared__ ushort Vs[64*64];   // rows = d, cols = key (from transposed Vt)
    __shared__ ushort Ps[64*64];

    const ushort* Qb = Qp + (size_t)(b*16 + h) * 2048 * 64;
    const ushort* Kb = Kp + (size_t)(b*16 + h) * 2048 * 64;
    const ushort* Vb = Vt + (size_t)(b*16 + h) * 64 * 2048;

    // load Q block r (swizzled)
    #pragma unroll
    for (int j = 0; j < 2; ++j) {
        int u = tid + j*256;          // 512 16B-units
        int row = u >> 3, col = u & 7;
        int slot = col ^ (row & 7);
        uint4 x = *reinterpret_cast<const uint4*>(Qb + (size_t)(r*64 + row)*64 + col*8);
        *reinterpret_cast<uint4*>(&Qs[row*64 + slot*8]) = x;
    }

    f32x4 acc_o[4];
    #pragma unroll
    for (int n = 0; n < 4; ++n) acc_o[n] = (f32x4){0.f,0.f,0.f,0.f};

    int c0 = r - 15; if (c0 < 0) c0 = 0;
    int c1 = r + 15; if (c1 > 31) c1 = 31;

    for (int c = c0; c <= c1; ++c) {
        __syncthreads();   // prior PV done reading Ks/Vs
        #pragma unroll
        for (int j = 0; j < 2; ++j) {
            int u = tid + j*256;
            int row = u >> 3, col = u & 7;
            int slot = col ^ (row & 7);
            uint4 kx = *reinterpret_cast<const uint4*>(Kb + (size_t)(c*64 + row)*64 + col*8);
            *reinterpret_cast<uint4*>(&Ks[row*64 + slot*8]) = kx;
            uint4 vx = *reinterpret_cast<const uint4*>(Vb + (size_t)row*2048 + c*64 + col*8);
            *reinterpret_cast<uint4*>(&Vs[row*64 + slot*8]) = vx;
        }
        __syncthreads();

        // scores: this wave's 16-row strip x 64 keys
        f32x4 sc[4];
        #pragma unroll
        for (int n = 0; n < 4; ++n) sc[n] = (f32x4){0.f,0.f,0.f,0.f};
        #pragma unroll
        for (int kk = 0; kk < 2; ++kk) {
            int arow = wave*16 + (lane & 15);
            int unit = kk*4 + (lane >> 4);
            bfx8 af = *reinterpret_cast<const bfx8*>(&Qs[arow*64 + (unit ^ (arow & 7))*8]);
            #pragma unroll
            for (int n = 0; n < 4; ++n) {
                int brow = n*16 + (lane & 15);
                bfx8 bfr = *reinterpret_cast<const bfx8*>(&Ks[brow*64 + (unit ^ (brow & 7))*8]);
                sc[n] = __builtin_amdgcn_mfma_f32_16x16x32_bf16(af, bfr, sc[n], 0,0,0);
            }
        }

        // wave-parallel softmax; row = wave*16 + (lane>>4)*4 + i, col = n*16 + (lane&15)
        float pn[4][4];
        #pragma unroll
        for (int i = 0; i < 4; ++i) {
            float m = sc[0][i];
            #pragma unroll
            for (int n = 1; n < 4; ++n) m = fmaxf(m, sc[n][i]);
            #pragma unroll
            for (int msk = 1; msk <= 8; msk <<= 1) m = fmaxf(m, __shfl_xor(m, msk));
            float ssum = 0.f;
            #pragma unroll
            for (int n = 0; n < 4; ++n) { float e = __expf((sc[n][i] - m)*0.125f); pn[n][i] = e; ssum += e; }
            #pragma unroll
            for (int msk = 1; msk <= 8; msk <<= 1) ssum += __shfl_xor(ssum, msk);
            float inv = 1.f / ssum;
            #pragma unroll
            for (int n = 0; n < 4; ++n) pn[n][i] *= inv;
        }
        // write normalized P to LDS (bf16, swizzled)
        #pragma unroll
        for (int n = 0; n < 4; ++n)
            #pragma unroll
            for (int i = 0; i < 4; ++i) {
                int row  = wave*16 + (lane >> 4)*4 + i;
                int colv = n*16 + (lane & 15);
                int slot = (colv >> 3) ^ (row & 7);
                Ps[row*64 + slot*8 + (colv & 7)] = f2bf(pn[n][i]);
            }
        __syncthreads();

        // O += P * V  (B-operand from transposed V: rows=d, contiguous along key)
        #pragma unroll
        for (int kk = 0; kk < 2; ++kk) {
            int arow = wave*16 + (lane & 15);
            int unit = kk*4 + (lane >> 4);
            bfx8 af = *reinterpret_cast<const bfx8*>(&Ps[arow*64 + (unit ^ (arow & 7))*8]);
            #pragma unroll
            for (int n = 0; n < 4; ++n) {
                int brow = n*16 + (lane & 15);   // d
                bfx8 bfr = *reinterpret_cast<const bfx8*>(&Vs[brow*64 + (unit ^ (brow & 7))*8]);
                acc_o[n] = __builtin_amdgcn_mfma_f32_16x16x32_bf16(af, bfr, acc_o[n], 0,0,0);
            }
        }
    }

    // write O strip to AO [B][S][E] (bf16 workspace), e = h*64 + d
    #pragma unroll
    for (int n = 0; n < 4; ++n)
        #pragma unroll
        for (int i = 0; i < 4; ++i) {
            int qrow = r*64 + wave*16 + (lane >> 4)*4 + i;
            int e    = h*64 + n*16 + (lane & 15);
            AO[((size_t)b*2048 + qrow)*1024 + e] = f2bf(acc_o[n][i]);
        }
}

extern "C" void kernel_launch(void* const* d_in, const int* in_sizes, int n_in,
                              void* d_out, int out_size, void* d_ws, size_t ws_size,
                              hipStream_t stream)
{
    (void)in_sizes; (void)n_in; (void)out_size; (void)ws_size;
    const float* q  = (const float*)d_in[0];
    const float* k  = (const float*)d_in[1];
    const float* v  = (const float*)d_in[2];
    const float* wq = (const float*)d_in[3];
    const float* wk = (const float*)d_in[4];
    const float* wv = (const float*)d_in[5];
    const float* wo = (const float*)d_in[6];

    ushort* ws = (ushort*)d_ws;
    const size_t IN_E = 4096ull * 1024ull;   // 4,194,304 elems
    const size_t W_E  = 1024ull * 1024ull;   // 1,048,576 elems
    ushort* qb  = ws;                  // bf16 query
    ushort* kb  = qb + IN_E;
    ushort* vb  = kb + IN_E;
    ushort* wqb = vb + IN_E;
    ushort* wkb = wqb + W_E;
    ushort* wvb = wkb + W_E;
    ushort* wob = wvb + W_E;
    ushort* Qp  = wob + W_E;           // [B][H][S][D]
    ushort* Kp  = Qp + IN_E;           // [B][H][S][D]
    ushort* Vt  = Kp + IN_E;           // [B][H][D][S]
    ushort* AO  = Vt + IN_E;           // [B][S][E]
    // total workspace: 33,554,432 ushorts = 64 MiB

    cvt_all<<<4096, 256, 0, stream>>>(q, k, v, wq, wk, wv, wo, ws);
    proj_kernel<<<dim3(256, 3), 256, 0, stream>>>(qb, kb, vb, wqb, wkb, wvb, Qp, Kp, Vt);
    attn_kernel<<<1024, 256, 0, stream>>>(Qp, Kp, Vt, AO);
    outproj_kernel<<<256, 256, 0, stream>>>(AO, wob, (float*)d_out);
}

// Round 3
// 259.524 us; speedup vs baseline: 1.1391x; 1.1391x over previous
//
#include <hip/hip_runtime.h>
#include <hip/hip_bf16.h>

typedef __attribute__((ext_vector_type(4))) float f32x4;
typedef __attribute__((ext_vector_type(8))) short bfx8;   // 8 bf16 = 4 VGPRs (MFMA A/B frag)

#define K_DIM 1024
#define N_DIM 1024

__device__ __forceinline__ ushort f2bf(float f) {
    uint u = __float_as_uint(f);
    u += 0x7fffu + ((u >> 16) & 1u);     // round-to-nearest-even
    return (ushort)(u >> 16);
}

// async global->LDS, 16B per lane. LDS dest must be wave-uniform base (lane*16 implicit).
__device__ __forceinline__ void gll16(const ushort* g, ushort* l) {
    __builtin_amdgcn_global_load_lds(
        (const __attribute__((address_space(1))) uint*)g,
        (__attribute__((address_space(3))) uint*)l,
        16, 0, 0);
}

// ---------------- f32 -> bf16 conversion of all 7 inputs ----------------
__global__ __launch_bounds__(256) void cvt_all(
    const float* __restrict__ q, const float* __restrict__ k, const float* __restrict__ v,
    const float* __restrict__ wq, const float* __restrict__ wk,
    const float* __restrict__ wv, const float* __restrict__ wo,
    ushort* __restrict__ ws)
{
    const int IN4 = 1 << 20;   // 4096*1024/4 float4 units per input
    const int W4  = 1 << 18;   // 1024*1024/4 per weight
    const int total = 3*IN4 + 4*W4;
    ushort4* dst4 = reinterpret_cast<ushort4*>(ws);
    for (int u = blockIdx.x*blockDim.x + threadIdx.x; u < total; u += gridDim.x*blockDim.x) {
        const float* src; int local, off;
        if (u < 3*IN4) {
            int op = u >> 20;
            local = u & (IN4-1);
            src = op==0 ? q : (op==1 ? k : v);
            off = op * IN4;
        } else {
            int t = u - 3*IN4;
            int op = t >> 18;
            local = t & (W4-1);
            src = op==0 ? wq : (op==1 ? wk : (op==2 ? wv : wo));
            off = 3*IN4 + op*W4;
        }
        float4 f = reinterpret_cast<const float4*>(src)[local];
        ushort4 o;
        o.x = f2bf(f.x); o.y = f2bf(f.y); o.z = f2bf(f.z); o.w = f2bf(f.w);
        dst4[off + local] = o;
    }
}

// ---------------- GEMM body: C[m][n] = sum_k A[m][k] * W[n][k], bf16 in ----
// 128x128 tile, BK=64, 4 waves (2x2 of 64x64), 16x16x32 bf16 MFMA.
// Staging: global_load_lds w16, pre-swizzled global source, linear LDS dest;
// frag reads use the matching XOR swizzle (involution) -> conflict-free.
// MODE 0: out bf16 [B][H][S][D]   (Q/K projection)
// MODE 1: out bf16 [B][H][D][S]   (V projection, transposed for PV reads)
// MODE 2: out f32  [M][N]         (final output -> d_out, reference dtype f32)
template<int MODE>
__device__ __forceinline__ void gemm_body(
    const ushort* __restrict__ A, const ushort* __restrict__ Bw,
    ushort* __restrict__ C, float* __restrict__ Cf,
    int blk, ushort* As, ushort* Bs)
{
    const int tid  = threadIdx.x;
    const int lane = tid & 63;
    const int wave = tid >> 6;
    const int tn = blk & 7;     // N/128 = 8
    const int tm = blk >> 3;    // M/128 = 32
    const int wr = wave >> 1, wc = wave & 1;

    // per-lane pre-swizzled source offsets (4 x 16B units per tile per lane)
    int goff[4];
    #pragma unroll
    for (int t = 0; t < 4; ++t) {
        int u = wave*256 + t*64 + lane;          // 1024 units per 128x64 tile
        int row = u >> 3;
        int col = (u & 7) ^ (row & 7);           // inverse swizzle on source
        goff[t] = row * K_DIM + col * 8;
    }
    const ushort* Abase = A  + (size_t)tm * 128 * K_DIM;
    const ushort* Bbase = Bw + (size_t)tn * 128 * K_DIM;

    f32x4 acc[4][4];
    #pragma unroll
    for (int a = 0; a < 4; ++a)
        #pragma unroll
        for (int b2 = 0; b2 < 4; ++b2)
            acc[a][b2] = (f32x4){0.f, 0.f, 0.f, 0.f};

    for (int k0 = 0; k0 < K_DIM; k0 += 64) {
        __syncthreads();   // prior compute done reading LDS
        #pragma unroll
        for (int t = 0; t < 4; ++t) {
            gll16(Abase + k0 + goff[t], As + (wave*256 + t*64)*8);
            gll16(Bbase + k0 + goff[t], Bs + (wave*256 + t*64)*8);
        }
        __syncthreads();   // compiler drains vmcnt(0) before barrier -> tiles ready
        #pragma unroll
        for (int kk = 0; kk < 2; ++kk) {
            bfx8 af[4], bfr[4];
            #pragma unroll
            for (int mi = 0; mi < 4; ++mi) {
                int row  = wr*64 + mi*16 + (lane & 15);
                int unit = kk*4 + (lane >> 4);
                af[mi] = *reinterpret_cast<const bfx8*>(&As[row*64 + (unit ^ (row & 7))*8]);
            }
            #pragma unroll
            for (int ni = 0; ni < 4; ++ni) {
                int row  = wc*64 + ni*16 + (lane & 15);
                int unit = kk*4 + (lane >> 4);
                bfr[ni] = *reinterpret_cast<const bfx8*>(&Bs[row*64 + (unit ^ (row & 7))*8]);
            }
            #pragma unroll
            for (int mi = 0; mi < 4; ++mi)
                #pragma unroll
                for (int ni = 0; ni < 4; ++ni)
                    acc[mi][ni] = __builtin_amdgcn_mfma_f32_16x16x32_bf16(af[mi], bfr[ni], acc[mi][ni], 0, 0, 0);
        }
    }
    // epilogue: D layout col = lane&15, row = (lane>>4)*4 + i
    #pragma unroll
    for (int mi = 0; mi < 4; ++mi)
      #pragma unroll
      for (int ni = 0; ni < 4; ++ni)
        #pragma unroll
        for (int i = 0; i < 4; ++i) {
            int gr = tm*128 + wr*64 + mi*16 + (lane >> 4)*4 + i;   // m: b*2048+s
            int gc = tn*128 + wc*64 + ni*16 + (lane & 15);         // n: h*64+d
            if constexpr (MODE == 0) {
                int b = gr >> 11, s = gr & 2047, h = gc >> 6, d = gc & 63;
                C[(((size_t)(b*16 + h))*2048 + s)*64 + d] = f2bf(acc[mi][ni][i]);
            } else if constexpr (MODE == 1) {
                int b = gr >> 11, s = gr & 2047, h = gc >> 6, d = gc & 63;
                C[(((size_t)(b*16 + h))*64 + d)*2048 + s] = f2bf(acc[mi][ni][i]);
            } else {
                Cf[(size_t)gr*N_DIM + gc] = acc[mi][ni][i];
            }
        }
}

__global__ __launch_bounds__(256) void proj_kernel(
    const ushort* __restrict__ qb, const ushort* __restrict__ kb, const ushort* __restrict__ vb,
    const ushort* __restrict__ wqb, const ushort* __restrict__ wkb, const ushort* __restrict__ wvb,
    ushort* __restrict__ Qp, ushort* __restrict__ Kp, ushort* __restrict__ Vt)
{
    __shared__ ushort As[128*64];
    __shared__ ushort Bs[128*64];
    int op = blockIdx.y;
    if (op == 0)      gemm_body<0>(qb, wqb, Qp, nullptr, blockIdx.x, As, Bs);
    else if (op == 1) gemm_body<0>(kb, wkb, Kp, nullptr, blockIdx.x, As, Bs);
    else              gemm_body<1>(vb, wvb, Vt, nullptr, blockIdx.x, As, Bs);
}

__global__ __launch_bounds__(256) void outproj_kernel(
    const ushort* __restrict__ AO, const ushort* __restrict__ wob, float* __restrict__ out)
{
    __shared__ ushort As[128*64];
    __shared__ ushort Bs[128*64];
    gemm_body<2>(AO, wob, nullptr, out, blockIdx.x, As, Bs);
}

// ---------------- block-sparse attention ----------------
// grid: b(2)*h(16)*r(32) = 1024 blocks, 256 threads (4 waves, 16-row strips).
// Double-buffered K/V via global_load_lds; Q/P share one wave-private buffer;
// one barrier per c-iteration; softmax without max-subtract.
__global__ __launch_bounds__(256) void attn_kernel(
    const ushort* __restrict__ Qp, const ushort* __restrict__ Kp,
    const ushort* __restrict__ Vt, ushort* __restrict__ AO)
{
    const int blk = blockIdx.x;
    const int r = blk & 31;
    const int h = (blk >> 5) & 15;
    const int b = blk >> 9;
    const int tid  = threadIdx.x;
    const int lane = tid & 63;
    const int wave = tid >> 6;

    __shared__ ushort Ks[2][4096];
    __shared__ ushort Vs[2][4096];
    __shared__ ushort QPs[4096];     // Q (prologue) then P (wave-private rows)

    const ushort* Qb = Qp + (size_t)(b*16 + h) * 2048 * 64;
    const ushort* Kb = Kp + (size_t)(b*16 + h) * 2048 * 64;
    const ushort* Vb = Vt + (size_t)(b*16 + h) * 64 * 2048;

    // per-lane pre-swizzled source offsets (2 units per 64x64 tile per lane)
    int koff[2], voff[2];
    #pragma unroll
    for (int t = 0; t < 2; ++t) {
        int u = wave*128 + t*64 + lane;          // 512 units per tile
        int row = u >> 3;
        int col = (u & 7) ^ (row & 7);
        koff[t] = row*64 + col*8;                // Q and K share this shape
        voff[t] = row*2048 + col*8;              // Vt rows are d, stride 2048
    }

    int c0 = r - 15; if (c0 < 0) c0 = 0;
    int c1 = r + 15; if (c1 > 31) c1 = 31;

    // prologue: stage Q + first K/V tile
    #pragma unroll
    for (int t = 0; t < 2; ++t) {
        gll16(Qb + (size_t)r*4096 + koff[t], QPs + (wave*128 + t*64)*8);
        gll16(Kb + (size_t)c0*4096 + koff[t], &Ks[0][(wave*128 + t*64)*8]);
        gll16(Vb + (size_t)c0*64   + voff[t], &Vs[0][(wave*128 + t*64)*8]);
    }
    __syncthreads();   // drains vmcnt(0): Q,K,V tile 0 in LDS

    // hoist Q fragments (loop-invariant, wave-private rows)
    bfx8 qf[2];
    #pragma unroll
    for (int kk = 0; kk < 2; ++kk) {
        int arow = wave*16 + (lane & 15);
        int unit = kk*4 + (lane >> 4);
        qf[kk] = *reinterpret_cast<const bfx8*>(&QPs[arow*64 + (unit ^ (arow & 7))*8]);
    }

    f32x4 acc_o[4];
    #pragma unroll
    for (int n = 0; n < 4; ++n) acc_o[n] = (f32x4){0.f,0.f,0.f,0.f};

    const float SC = 0.125f * 1.44269504f;    // scale folded with log2(e)
    int cur = 0;
    for (int c = c0; c <= c1; ++c) {
        // prefetch next K/V into the other buffer (flies during compute)
        if (c < c1) {
            #pragma unroll
            for (int t = 0; t < 2; ++t) {
                gll16(Kb + (size_t)(c+1)*4096 + koff[t], &Ks[cur^1][(wave*128 + t*64)*8]);
                gll16(Vb + (size_t)(c+1)*64   + voff[t], &Vs[cur^1][(wave*128 + t*64)*8]);
            }
        }

        // QK^T: wave's 16-row strip x 64 keys
        f32x4 sc[4];
        #pragma unroll
        for (int n = 0; n < 4; ++n) sc[n] = (f32x4){0.f,0.f,0.f,0.f};
        #pragma unroll
        for (int kk = 0; kk < 2; ++kk) {
            #pragma unroll
            for (int n = 0; n < 4; ++n) {
                int brow = n*16 + (lane & 15);
                int unit = kk*4 + (lane >> 4);
                bfx8 kf = *reinterpret_cast<const bfx8*>(&Ks[cur][brow*64 + (unit ^ (brow & 7))*8]);
                sc[n] = __builtin_amdgcn_mfma_f32_16x16x32_bf16(qf[kk], kf, sc[n], 0,0,0);
            }
        }

        // per-pair softmax, no max-subtract (scores |s*0.125| < ~12, exp2 safe in f32)
        float pn[4][4]; float inv[4];
        #pragma unroll
        for (int i = 0; i < 4; ++i) {
            float ssum = 0.f;
            #pragma unroll
            for (int n = 0; n < 4; ++n) { float e = exp2f(sc[n][i]*SC); pn[n][i] = e; ssum += e; }
            #pragma unroll
            for (int msk = 1; msk <= 8; msk <<= 1) ssum += __shfl_xor(ssum, msk);
            inv[i] = __builtin_amdgcn_rcpf(ssum);
        }
        // write normalized P (bf16, swizzled) — wave-private rows, no barrier needed
        #pragma unroll
        for (int n = 0; n < 4; ++n)
            #pragma unroll
            for (int i = 0; i < 4; ++i) {
                int row  = wave*16 + (lane >> 4)*4 + i;
                int colv = n*16 + (lane & 15);
                QPs[row*64 + ((colv >> 3) ^ (row & 7))*8 + (colv & 7)] = f2bf(pn[n][i]*inv[i]);
            }

        // O += P * V
        #pragma unroll
        for (int kk = 0; kk < 2; ++kk) {
            int arow = wave*16 + (lane & 15);
            int unit = kk*4 + (lane >> 4);
            bfx8 pf = *reinterpret_cast<const bfx8*>(&QPs[arow*64 + (unit ^ (arow & 7))*8]);
            #pragma unroll
            for (int n = 0; n < 4; ++n) {
                int brow = n*16 + (lane & 15);   // d
                bfx8 vf = *reinterpret_cast<const bfx8*>(&Vs[cur][brow*64 + (unit ^ (brow & 7))*8]);
                acc_o[n] = __builtin_amdgcn_mfma_f32_16x16x32_bf16(pf, vf, acc_o[n], 0,0,0);
            }
        }

        __syncthreads();   // drains vmcnt(0): prefetch landed; all reads of cur done
        cur ^= 1;
    }

    // write O strip to AO [B][S][E] (bf16 workspace), e = h*64 + d
    #pragma unroll
    for (int n = 0; n < 4; ++n)
        #pragma unroll
        for (int i = 0; i < 4; ++i) {
            int qrow = r*64 + wave*16 + (lane >> 4)*4 + i;
            int e    = h*64 + n*16 + (lane & 15);
            AO[((size_t)b*2048 + qrow)*1024 + e] = f2bf(acc_o[n][i]);
        }
}

extern "C" void kernel_launch(void* const* d_in, const int* in_sizes, int n_in,
                              void* d_out, int out_size, void* d_ws, size_t ws_size,
                              hipStream_t stream)
{
    (void)in_sizes; (void)n_in; (void)out_size; (void)ws_size;
    const float* q  = (const float*)d_in[0];
    const float* k  = (const float*)d_in[1];
    const float* v  = (const float*)d_in[2];
    const float* wq = (const float*)d_in[3];
    const float* wk = (const float*)d_in[4];
    const float* wv = (const float*)d_in[5];
    const float* wo = (const float*)d_in[6];

    ushort* ws = (ushort*)d_ws;
    const size_t IN_E = 4096ull * 1024ull;   // 4,194,304 elems
    const size_t W_E  = 1024ull * 1024ull;   // 1,048,576 elems
    ushort* qb  = ws;                  // bf16 query
    ushort* kb  = qb + IN_E;
    ushort* vb  = kb + IN_E;
    ushort* wqb = vb + IN_E;
    ushort* wkb = wqb + W_E;
    ushort* wvb = wkb + W_E;
    ushort* wob = wvb + W_E;
    ushort* Qp  = wob + W_E;           // [B][H][S][D]
    ushort* Kp  = Qp + IN_E;           // [B][H][S][D]
    ushort* Vt  = Kp + IN_E;           // [B][H][D][S]
    ushort* AO  = Vt + IN_E;           // [B][S][E]
    // total workspace: 33,554,432 ushorts = 64 MiB

    cvt_all<<<4096, 256, 0, stream>>>(q, k, v, wq, wk, wv, wo, ws);
    proj_kernel<<<dim3(256, 3), 256, 0, stream>>>(qb, kb, vb, wqb, wkb, wvb, Qp, Kp, Vt);
    attn_kernel<<<1024, 256, 0, stream>>>(Qp, Kp, Vt, AO);
    outproj_kernel<<<256, 256, 0, stream>>>(AO, wob, (float*)d_out);
}